// Round 4
// baseline (921.911 us; speedup 1.0000x reference)
//
#include <hip/hip_runtime.h>
#include <hip/hip_bf16.h>
#include <type_traits>
#include <utility>

// ---------------------------------------------------------------------------
// C = tril(A @ B), N=8192, A,B lower-triangular fp32.
// convert A->bf16; transpose B->bf16 Bt[n][k] via MFMA-identity trick (no LDS
// scalar serialization); bf16 MFMA GEMM over lower 128x128 tiles with
// K in [bj*128,(bi+1)*128), 8x8 supertiles far-from-diagonal first.
// GEMM epilogue round-trips through LDS for full-cache-line C stores.
// ---------------------------------------------------------------------------

static constexpr int MATN = 8192;

typedef __attribute__((ext_vector_type(8))) short  s8v;
typedef __attribute__((ext_vector_type(4))) short  s4h;
typedef __attribute__((ext_vector_type(8))) __bf16 b8v;
typedef __attribute__((ext_vector_type(4))) float  f4v;

template <typename V, typename = void>
struct mfma_ok : std::false_type {};
template <typename V>
struct mfma_ok<V, std::void_t<decltype(__builtin_amdgcn_mfma_f32_16x16x32_bf16(
    std::declval<V>(), std::declval<V>(), std::declval<f4v>(), 0, 0, 0))>>
    : std::true_type {};
using abv = std::conditional_t<mfma_ok<b8v>::value, b8v, s8v>;

__device__ __forceinline__ short f2bf(float f) {
  unsigned u = __builtin_bit_cast(unsigned, f);
  unsigned r = (u + 0x7fffu + ((u >> 16) & 1u)) >> 16;
  return (short)r;
}

template <typename V>
__device__ __forceinline__ void set_bits(V& v, int i, short bits) {
  if constexpr (std::is_same_v<V, s8v>) v[i] = bits;
  else v[i] = __builtin_bit_cast(__bf16, bits);
}

__device__ __forceinline__ void async16(void* lds, const void* g) {
  __builtin_amdgcn_global_load_lds(
      (const __attribute__((address_space(1))) unsigned int*)g,
      (__attribute__((address_space(3))) unsigned int*)lds, 16, 0, 0);
}

// largest k with k(k+1)/2 <= id
__device__ __forceinline__ int tri_decode(int id) {
  int k = (int)((sqrtf(8.0f * (float)id + 1.0f) - 1.0f) * 0.5f);
  while ((k + 1) * (k + 2) / 2 <= id) k++;
  while (k * (k + 1) / 2 > id) k--;
  return k;
}

// ---------------------------------------------------------------------------
// Kernel 1: A (fp32) -> Abf (bf16), same layout; upper chunks write zeros
// without loading.
// ---------------------------------------------------------------------------
__global__ __launch_bounds__(256) void convert_A_k(const float* __restrict__ A,
                                                   short* __restrict__ Abf) {
  int gid  = blockIdx.x * 256 + threadIdx.x;
  int base = gid * 8;
  int row  = base >> 13;
  int col  = base & 8191;
  s8v o = {};
  if (col <= row) {
    f4v v0 = *(const f4v*)&A[base];
    f4v v1 = *(const f4v*)&A[base + 4];
#pragma unroll
    for (int i = 0; i < 4; i++) { o[i] = f2bf(v0[i]); o[4 + i] = f2bf(v1[i]); }
  }
  *(s8v*)&Abf[base] = o;
}

// ---------------------------------------------------------------------------
// Kernel 2: MFMA-identity transpose. Block = 4 waves covers k-span 64 x
// n-span 32. Wave w: A-frag = B[k0w+ln][n0+quad*8+j] (vector loads, bf16);
// identity B-frag I_s picks column n0+16s+q -> D_s[i][q] = B[k0w+i][n0+16s+q]
// lands with lane q=ln holding 4 CONSECUTIVE k' (quad*4+r) -> 8B stores of
// Bt[n][k]. Zero LDS. B-read lines and Bt-write lines block-exclusive.
// ---------------------------------------------------------------------------
__global__ __launch_bounds__(256) void mfma_transpose_B(const float* __restrict__ B,
                                                        short* __restrict__ Bt) {
  int kb = blockIdx.x, nb = blockIdx.y;
  int K0 = kb * 64, n0 = nb * 32;
  int tid = threadIdx.x;
  if (K0 + 63 < n0) {                          // Bt tile structurally zero
    int row = tid >> 3, ch = tid & 7;
    s8v z = {};
    *(s8v*)&Bt[(size_t)(n0 + row) * MATN + K0 + ch * 8] = z;
    return;
  }
  int wave = tid >> 6, lane = tid & 63;
  int quad = lane >> 4, ln = lane & 15;
  int k0w = K0 + wave * 16;

  const float* src = &B[(size_t)(k0w + ln) * MATN + n0 + quad * 8];
  f4v v0 = *(const f4v*)src;
  f4v v1 = *(const f4v*)(src + 4);
  abv af;
#pragma unroll
  for (int i = 0; i < 4; i++) {
    set_bits(af, i,     f2bf(v0[i]));
    set_bits(af, 4 + i, f2bf(v1[i]));
  }
  abv I0, I1;
#pragma unroll
  for (int j = 0; j < 8; j++) {
    set_bits(I0, j, (short)((8 * quad + j == ln)      ? 0x3F80 : 0));
    set_bits(I1, j, (short)((8 * quad + j == ln + 16) ? 0x3F80 : 0));
  }
  f4v d0 = {}, d1 = {};
  d0 = __builtin_amdgcn_mfma_f32_16x16x32_bf16(af, I0, d0, 0, 0, 0);
  d1 = __builtin_amdgcn_mfma_f32_16x16x32_bf16(af, I1, d1, 0, 0, 0);

  s4h o0, o1;
#pragma unroll
  for (int r = 0; r < 4; r++) { o0[r] = f2bf(d0[r]); o1[r] = f2bf(d1[r]); }
  *(s4h*)&Bt[(size_t)(n0 + ln) * MATN + k0w + quad * 4]      = o0;
  *(s4h*)&Bt[(size_t)(n0 + 16 + ln) * MATN + k0w + quad * 4] = o1;
}

// ---------------------------------------------------------------------------
// Kernel 3: triangular bf16 MFMA GEMM. Grid 4096; 8x8-tile supertiles,
// far-from-diagonal first. Epilogue via LDS for full-line C stores.
// ---------------------------------------------------------------------------
__global__ __launch_bounds__(256) void gemm_tril(const short* __restrict__ Abf,
                                                 const short* __restrict__ Btb,
                                                 float* __restrict__ C) {
  int id = blockIdx.x;
  int tid = threadIdx.x;
  int bi, bj;
  if (id < 2304) {                             // lower supertiles, D desc
    int s = id >> 6;
    int t = tri_decode(s);
    int J = s - t * (t + 1) / 2;
    int I = J + 7 - t;
    int li = 7 - ((id >> 3) & 7);
    int lj = id & 7;
    bi = I * 8 + li;
    bj = J * 8 + lj;
  } else {                                     // upper supertiles
    int q = id - 2304;
    int s = q >> 6;
    int r = tri_decode(s);
    int I = s - r * (r + 1) / 2;
    int J = r + 1;
    bi = I * 8 + ((q >> 3) & 7);
    bj = J * 8 + (q & 7);
  }

  if (bi < bj) {                               // zero tile (full-line stores)
    f4v z = {};
    size_t base = (size_t)bi * 128 * MATN + (size_t)bj * 128;
#pragma unroll
    for (int t = 0; t < 16; t++) {
      int c = t * 256 + tid;
      int r2 = c >> 5, cc = (c & 31) * 4;
      *(f4v*)&C[base + (size_t)r2 * MATN + cc] = z;
    }
    return;
  }

  __shared__ __align__(16) char smem[16384];
  short* As = (short*)smem;
  short* Bs = (short*)(smem + 8192);

  int wave = tid >> 6, lane = tid & 63;
  int quad = lane >> 4, ln = lane & 15;
  int wm = wave >> 1, wn = wave & 1;

  int row0 = bi * 128, col0 = bj * 128;
  f4v acc[4][4] = {};

  int r0 = tid >> 2, c0 = (tid & 3) * 8;
  int r1 = 64 + r0;
  char* lA0 = (char*)As + wave * 1024;
  char* lA1 = (char*)As + 4096 + wave * 1024;
  char* lB0 = (char*)Bs + wave * 1024;
  char* lB1 = (char*)Bs + 4096 + wave * 1024;

  int kend = (bi + 1) * 128;
  for (int kt = col0; kt < kend; kt += 32) {
    __syncthreads();
    async16(lA0, &Abf[(size_t)(row0 + r0) * MATN + kt + c0]);
    async16(lA1, &Abf[(size_t)(row0 + r1) * MATN + kt + c0]);
    async16(lB0, &Btb[(size_t)(col0 + r0) * MATN + kt + c0]);
    async16(lB1, &Btb[(size_t)(col0 + r1) * MATN + kt + c0]);
    __syncthreads();

    abv a[4], b[4];
#pragma unroll
    for (int t = 0; t < 4; t++) {
      a[t] = *(const abv*)&As[(wm * 64 + t * 16 + ln) * 32 + quad * 8];
      b[t] = *(const abv*)&Bs[(wn * 64 + t * 16 + ln) * 32 + quad * 8];
    }
#pragma unroll
    for (int tm = 0; tm < 4; tm++)
#pragma unroll
      for (int tn = 0; tn < 4; tn++)
        acc[tm][tn] = __builtin_amdgcn_mfma_f32_16x16x32_bf16(
            a[tm], b[tn], acc[tm][tn], 0, 0, 0);
  }

  // Epilogue: 4 rounds of 32 rows through LDS -> f4v full-line C stores.
  bool diag = (bi == bj);
  float* Ct = (float*)smem;                    // 32 x 128 floats = 16KB
#pragma unroll
  for (int tm = 0; tm < 4; tm++) {
    __syncthreads();                           // LDS free (K-loop / prev round)
#pragma unroll
    for (int tn = 0; tn < 4; tn++) {
      int col = wn * 64 + tn * 16 + ln;
      int gc = col0 + col;
#pragma unroll
      for (int r = 0; r < 4; r++) {
        int lrow = wm * 16 + quad * 4 + r;
        int gr = row0 + wm * 64 + tm * 16 + quad * 4 + r;
        float v = acc[tm][tn][r];
        if (diag && gr < gc) v = 0.0f;
        Ct[lrow * 128 + col] = v;
      }
    }
    __syncthreads();
#pragma unroll
    for (int w = 0; w < 4; w++) {
      int chunk = w * 256 + tid;
      int lrow = chunk >> 5, c4 = (chunk & 31) * 4;
      int gr = row0 + (lrow >> 4) * 64 + tm * 16 + (lrow & 15);
      *(f4v*)&C[(size_t)gr * MATN + col0 + c4] = *(const f4v*)&Ct[lrow * 128 + c4];
    }
  }
}

// ---------------------------------------------------------------------------
// Fallback: correct fp32 LDS-tiled GEMM (only if ws too small).
// ---------------------------------------------------------------------------
__global__ __launch_bounds__(256) void gemm_tril_f32(const float* __restrict__ A,
                                                     const float* __restrict__ B,
                                                     float* __restrict__ C) {
  int bj = blockIdx.x, bi = blockIdx.y;
  int tid = threadIdx.x;
  int row0 = bi * 64, col0 = bj * 64;
  if (bi < bj) {
    f4v z = {};
#pragma unroll
    for (int t = 0; t < 4; t++) {
      int c = t * 256 + tid;
      int r = c >> 4, cc = (c & 15) * 4;
      *(f4v*)&C[(size_t)(row0 + r) * MATN + col0 + cc] = z;
    }
    return;
  }
  __shared__ float As[64][17];
  __shared__ float Bs[16][65];
  int tx = tid & 15, ty = tid >> 4;
  float acc[4][4] = {};
  int kendf = (bi + 1) * 64;
  for (int kt = col0; kt < kendf; kt += 16) {
    __syncthreads();
#pragma unroll
    for (int t = 0; t < 4; t++) {
      int c = t * 256 + tid;
      int r = c >> 4, k = c & 15;
      As[r][k] = A[(size_t)(row0 + r) * MATN + kt + k];
    }
#pragma unroll
    for (int t = 0; t < 4; t++) {
      int c = t * 256 + tid;
      int k = c >> 6, n = c & 63;
      Bs[k][n] = B[(size_t)(kt + k) * MATN + col0 + n];
    }
    __syncthreads();
#pragma unroll
    for (int k = 0; k < 16; k++) {
      float av[4], bv[4];
#pragma unroll
      for (int i = 0; i < 4; i++) av[i] = As[ty * 4 + i][k];
#pragma unroll
      for (int j = 0; j < 4; j++) bv[j] = Bs[k][tx * 4 + j];
#pragma unroll
      for (int i = 0; i < 4; i++)
#pragma unroll
        for (int j = 0; j < 4; j++) acc[i][j] += av[i] * bv[j];
    }
  }
#pragma unroll
  for (int i = 0; i < 4; i++)
#pragma unroll
    for (int j = 0; j < 4; j++) {
      int gr = row0 + ty * 4 + i, gc = col0 + tx * 4 + j;
      C[(size_t)gr * MATN + gc] = (gr >= gc) ? acc[i][j] : 0.0f;
    }
}

// ---------------------------------------------------------------------------
extern "C" void kernel_launch(void* const* d_in, const int* in_sizes, int n_in,
                              void* d_out, int out_size, void* d_ws, size_t ws_size,
                              hipStream_t stream) {
  const float* A = (const float*)d_in[0];
  const float* B = (const float*)d_in[1];
  float* C = (float*)d_out;

  const size_t need = 2ull * MATN * MATN * sizeof(short);  // 256 MiB
  if (ws_size >= need) {
    short* Abf = (short*)d_ws;
    short* Btb = Abf + (size_t)MATN * MATN;
    convert_A_k<<<(MATN * (size_t)MATN) / 8 / 256, 256, 0, stream>>>(A, Abf);
    mfma_transpose_B<<<dim3(MATN / 64, MATN / 32), 256, 0, stream>>>(B, Btb);
    gemm_tril<<<4096, 256, 0, stream>>>(Abf, Btb, C);
  } else {
    gemm_tril_f32<<<dim3(MATN / 64, MATN / 64), 256, 0, stream>>>(A, B, C);
  }
}